// Round 1
// baseline (32.231 us; speedup 1.0000x reference)
//
#include <hip/hip_runtime.h>

// Problem constants (from reference setup_inputs)
#define BB 32
#define TT 512
#define DD 256
#define MAXDUR 4096
#define D4 (DD / 4)          // 64 float4 per row
#define FPB 64               // frames per block in gather kernel

// Kernel 1: per-batch inclusive scan of durations.
// grid = BB blocks, block = TT threads. Writes cum[b][t] to ws and
// total[b] (as float) to the output tail.
__global__ __launch_bounds__(TT)
void lr_scan_kernel(const int* __restrict__ dur,
                    int* __restrict__ cum,
                    float* __restrict__ out_total) {
    __shared__ int s[TT];
    const int b = blockIdx.x;
    const int t = threadIdx.x;
    s[t] = dur[b * TT + t];
    __syncthreads();
    // Hillis-Steele inclusive scan over 512 elements (9 rounds)
    #pragma unroll
    for (int off = 1; off < TT; off <<= 1) {
        int v = (t >= off) ? s[t - off] : 0;
        __syncthreads();
        s[t] += v;
        __syncthreads();
    }
    cum[b * TT + t] = s[t];
    if (t == TT - 1) {
        out_total[b] = (float)s[t];   // tuple output promoted to f32 on concat
    }
}

// Kernel 2: gather + zero-fill.
// grid = BB * (MAXDUR/FPB) blocks, block = 256 threads.
// Each block: one batch, FPB consecutive frames.
__global__ __launch_bounds__(256)
void lr_gather_kernel(const float* __restrict__ x,
                      const int* __restrict__ cum,
                      float* __restrict__ out) {
    __shared__ int scum[TT];
    __shared__ int sidx[FPB];

    const int blocksPerBatch = MAXDUR / FPB;   // 64
    const int b = blockIdx.x / blocksPerBatch;
    const int chunk = blockIdx.x % blocksPerBatch;
    const int f0 = chunk * FPB;
    const int tid = threadIdx.x;

    // stage cum row into LDS (512 ints = 2 KB)
    #pragma unroll
    for (int i = tid; i < TT; i += 256) scum[i] = cum[b * TT + i];
    __syncthreads();

    const int total = scum[TT - 1];

    // one thread per frame: upper_bound(scum, f) then clamp; -1 marks invalid
    if (tid < FPB) {
        const int f = f0 + tid;
        int lo = 0, hi = TT;               // first index with scum[idx] > f
        #pragma unroll
        for (int it = 0; it < 9; ++it) {   // ceil(log2(512)) = 9
            int mid = (lo + hi) >> 1;
            if (lo < hi) {
                if (scum[mid] <= f) lo = mid + 1; else hi = mid;
            }
        }
        int idx = lo < TT - 1 ? lo : TT - 1;
        sidx[tid] = (f < total) ? idx : -1;
    }
    __syncthreads();

    // copy rows: 64 float4 per frame; wave w handles frame (it*4 + w)
    const int vec = tid & 63;        // float4 index within row
    const int fl  = tid >> 6;        // 0..3 (wave id)
    const float4* __restrict__ x4 = (const float4*)x;
    float4* __restrict__ out4 = (float4*)out;
    const float4 zero = make_float4(0.f, 0.f, 0.f, 0.f);

    #pragma unroll
    for (int it = 0; it < FPB / 4; ++it) {
        const int flocal = it * 4 + fl;
        const int f = f0 + flocal;
        const int idx = sidx[flocal];
        float4 v = zero;
        if (idx >= 0) {
            v = x4[((size_t)b * TT + idx) * D4 + vec];
        }
        out4[((size_t)b * MAXDUR + f) * D4 + vec] = v;
    }
}

extern "C" void kernel_launch(void* const* d_in, const int* in_sizes, int n_in,
                              void* d_out, int out_size, void* d_ws, size_t ws_size,
                              hipStream_t stream) {
    const float* x   = (const float*)d_in[0];   // (B,T,D) f32
    const int*   dur = (const int*)d_in[1];     // (B,T) i32
    // d_in[2] = max_dur scalar (4096) — compile-time constant here

    float* out = (float*)d_out;                               // (B,MAXDUR,D) f32
    float* out_total = out + (size_t)BB * MAXDUR * DD;        // B floats (tail)
    int* cum = (int*)d_ws;                                    // 32*512 ints

    lr_scan_kernel<<<BB, TT, 0, stream>>>(dur, cum, out_total);
    lr_gather_kernel<<<BB * (MAXDUR / FPB), 256, 0, stream>>>(x, cum, out);
}

// Round 2
// 28.120 us; speedup vs baseline: 1.1462x; 1.1462x over previous
//
#include <hip/hip_runtime.h>

// Problem constants (from reference setup_inputs)
#define BB 32
#define TT 512
#define DD 256
#define MAXDUR 4096
#define D4 (DD / 4)          // 64 float4 per row
#define FPB 64               // frames per block

// Fused kernel: per-block cumsum recompute + searchsorted + gather.
// grid = BB * (MAXDUR/FPB) = 2048 blocks, block = 256 threads.
__global__ __launch_bounds__(256)
void lr_fused_kernel(const float* __restrict__ x,
                     const int* __restrict__ dur,
                     float* __restrict__ out,
                     float* __restrict__ out_total) {
    __shared__ int scum[TT];     // inclusive cumsum of the batch's durations
    __shared__ int sp[256];      // pair-sum scan buffer
    __shared__ int sidx[FPB];    // frame -> row index (-1 = zero-fill)

    const int blocksPerBatch = MAXDUR / FPB;       // 64
    const int b = blockIdx.x / blocksPerBatch;
    const int chunk = blockIdx.x % blocksPerBatch;
    const int f0 = chunk * FPB;
    const int tid = threadIdx.x;

    // ---- in-block inclusive scan of 512 durations (2 elems/thread) ----
    int2 d2 = ((const int2*)(dur + b * TT))[tid];  // coalesced 8B/lane
    const int a0 = d2.x;
    const int a1 = d2.x + d2.y;
    sp[tid] = a1;
    __syncthreads();
    #pragma unroll
    for (int off = 1; off < 256; off <<= 1) {      // 8 rounds
        int v = (tid >= off) ? sp[tid - off] : 0;
        __syncthreads();
        sp[tid] += v;
        __syncthreads();
    }
    const int off_excl = sp[tid] - a1;             // exclusive prefix of pairs
    scum[2 * tid]     = off_excl + a0;
    scum[2 * tid + 1] = off_excl + a1;
    __syncthreads();

    const int total = scum[TT - 1];
    if (chunk == 0 && tid == 0) {
        out_total[b] = (float)total;               // tuple tail, promoted to f32
    }

    // ---- one thread per frame: upper_bound(scum, f), clamp, validity ----
    if (tid < FPB) {
        const int f = f0 + tid;
        int lo = 0, hi = TT;                       // first idx with scum[idx] > f
        #pragma unroll
        for (int it = 0; it < 9; ++it) {           // ceil(log2(512)) = 9
            int mid = (lo + hi) >> 1;
            if (lo < hi) {
                if (scum[mid] <= f) lo = mid + 1; else hi = mid;
            }
        }
        int idx = lo < TT - 1 ? lo : TT - 1;
        sidx[tid] = (f < total) ? idx : -1;
    }
    __syncthreads();

    // ---- stream rows: wave w copies frame it*4+w, 16B/lane coalesced ----
    const int vec = tid & 63;        // float4 index within row
    const int fl  = tid >> 6;        // wave id 0..3
    const float4* __restrict__ x4 = (const float4*)x;
    float4* __restrict__ out4 = (float4*)out;
    const float4 zero = make_float4(0.f, 0.f, 0.f, 0.f);

    #pragma unroll
    for (int it = 0; it < FPB / 4; ++it) {
        const int flocal = it * 4 + fl;
        const int f = f0 + flocal;
        const int idx = sidx[flocal];
        float4 v = zero;
        if (idx >= 0) {
            v = x4[((size_t)b * TT + idx) * D4 + vec];
        }
        out4[((size_t)b * MAXDUR + f) * D4 + vec] = v;
    }
}

extern "C" void kernel_launch(void* const* d_in, const int* in_sizes, int n_in,
                              void* d_out, int out_size, void* d_ws, size_t ws_size,
                              hipStream_t stream) {
    const float* x   = (const float*)d_in[0];   // (B,T,D) f32
    const int*   dur = (const int*)d_in[1];     // (B,T) i32
    // d_in[2] = max_dur scalar (4096) — compile-time constant here

    float* out = (float*)d_out;                               // (B,MAXDUR,D) f32
    float* out_total = out + (size_t)BB * MAXDUR * DD;        // B floats (tail)

    lr_fused_kernel<<<BB * (MAXDUR / FPB), 256, 0, stream>>>(x, dur, out, out_total);
}